// Round 3
// baseline (1596.119 us; speedup 1.0000x reference)
//
#include <hip/hip_runtime.h>
#include <hip/hip_bf16.h>

#define N_IN   200000
#define N_OUT  600000
#define KOFF   27
#define PPAIR  150000
#define NPAIR  (KOFF * PPAIR)       // 4,050,000
#define C      96
#define BN_EPS 1e-5f

using bf16x8 = __attribute__((ext_vector_type(8))) __bf16;
using f32x4  = __attribute__((ext_vector_type(4))) float;
using u32x2  = __attribute__((ext_vector_type(2))) unsigned int;

static __device__ __forceinline__ unsigned short f2b(float x) {
    __hip_bfloat16 h = __float2bfloat16(x);
    return *reinterpret_cast<unsigned short*>(&h);
}
static __device__ __forceinline__ float b_lo(unsigned int u) { return __uint_as_float(u << 16); }
static __device__ __forceinline__ float b_hi(unsigned int u) { return __uint_as_float(u & 0xffff0000u); }

// ---- feats fp32 -> bf16, 8 elems/thread. 19,200,000 = 9375*256*8 exactly.
__global__ void cvt_feats(const float* __restrict__ src, unsigned short* __restrict__ dst) {
    int t = blockIdx.x * 256 + threadIdx.x;
    const float4* s4 = (const float4*)src;
    float4 a = s4[2 * t], b = s4[2 * t + 1];
    union { unsigned short u[8]; uint4 v; } r;
    r.u[0] = f2b(a.x); r.u[1] = f2b(a.y); r.u[2] = f2b(a.z); r.u[3] = f2b(a.w);
    r.u[4] = f2b(b.x); r.u[5] = f2b(b.y); r.u[6] = f2b(b.z); r.u[7] = f2b(b.w);
    ((uint4*)dst)[t] = r.v;
}

// ---- weight [k][c_in][c_out] fp32 -> wt [k][c_out][c_in] bf16
__global__ void cvt_w(const float* __restrict__ w, unsigned short* __restrict__ wt) {
    int t = blockIdx.x * 256 + threadIdx.x;   // 972*256 = 248832 exactly
    int k = t / 9216;
    int rem = t - k * 9216;
    int o = rem / 96;
    int i = rem - o * 96;
    wt[t] = f2b(w[k * 9216 + i * 96 + o]);
}

// ---- counting sort metadata ----------------------------------------------
// hist + local rank in ONE pass: the atomicAdd return value IS the local rank.
// lrank fits uint8 (max multiplicity of one out site << 255).
__global__ void k_hist(const int* __restrict__ out_idx, int* __restrict__ counts,
                       unsigned char* __restrict__ lrank) {
    int t = blockIdx.x * 256 + threadIdx.x;
    if (t < NPAIR) lrank[t] = (unsigned char)atomicAdd(&counts[out_idx[t]], 1);
}

__global__ void k_bsum(const int* __restrict__ counts, int* __restrict__ bsum) {
    __shared__ int ls[256];
    int b = blockIdx.x, t = threadIdx.x;
    int base = b * 1024 + t * 4;
    int s = 0;
#pragma unroll
    for (int j = 0; j < 4; j++) { int i = base + j; if (i < N_OUT) s += counts[i]; }
    ls[t] = s;
    __syncthreads();
    for (int off = 128; off > 0; off >>= 1) {
        if (t < off) ls[t] += ls[t + off];
        __syncthreads();
    }
    if (t == 0) bsum[b] = ls[0];
}

__global__ void k_scan_bsum(const int* __restrict__ bsum, int* __restrict__ bsum_ex) {
    __shared__ int sc[1024];
    int t = threadIdx.x;
    int v = (t < 586) ? bsum[t] : 0;
    sc[t] = v;
    __syncthreads();
    for (int off = 1; off < 1024; off <<= 1) {
        int add = (t >= off) ? sc[t - off] : 0;
        __syncthreads();
        sc[t] += add;
        __syncthreads();
    }
    bsum_ex[t] = sc[t] - v;   // exclusive
}

// IN-PLACE: csr aliases counts (reads happen before first barrier, writes after).
__global__ void k_scan_local(int* __restrict__ csr, const int* __restrict__ bsum_ex) {
    __shared__ int sc[256];
    int b = blockIdx.x, t = threadIdx.x;
    int base = b * 1024 + t * 4;
    int c[4];
    int s = 0;
#pragma unroll
    for (int j = 0; j < 4; j++) {
        int i = base + j;
        c[j] = (i < N_OUT) ? csr[i] : 0;
        s += c[j];
    }
    sc[t] = s;
    __syncthreads();
    for (int off = 1; off < 256; off <<= 1) {
        int add = (t >= off) ? sc[t - off] : 0;
        __syncthreads();
        sc[t] += add;
        __syncthreads();
    }
    int run = bsum_ex[b] + sc[t] - s;
#pragma unroll
    for (int j = 0; j < 4; j++) {
        int i = base + j;
        if (i < N_OUT) {
            csr[i] = run;
            run += c[j];
            if (i == N_OUT - 1) csr[N_OUT] = run;
        }
    }
}

// perm[sorted_pos] = pair index (deterministic: same order as previous rounds).
__global__ void k_perm(const int* __restrict__ out_idx, const unsigned char* __restrict__ lrank,
                       const int* __restrict__ csr, int* __restrict__ perm) {
    int t = blockIdx.x * 256 + threadIdx.x;
    if (t < NPAIR) perm[csr[out_idx[t]] + (int)lrank[t]] = t;
}

// ---- Phase A: gather -> transposed MFMA -> SEQUENTIAL streaming store -----
// contrib is written in PAIR order: each wave emits 16 consecutive 192B rows
// = 3KB fully contiguous. No rank lookup, no LDS, no barrier, no shfl.
// mfma(b, a, acc): lane (quad,l16) holds channels n*16+quad*4+{0..3} of pair
// row (row0 + wave*16 + l16).
__global__ __launch_bounds__(256, 8) void contrib_k(
    const unsigned short* __restrict__ fb,   // feats bf16 [N_IN][96]
    const unsigned short* __restrict__ wt,   // weight bf16 [27][96(out)][96(in)]
    const int* __restrict__ in_idx,
    unsigned short* __restrict__ contrib)    // [NPAIR][96] bf16, PAIR order
{
    const int t    = threadIdx.x;
    const int k    = blockIdx.y;
    const int row0 = blockIdx.x * 64;
    const long kp  = (long)k * PPAIR;

    const int wave = t >> 6, lane = t & 63;
    const int quad = lane >> 4, l16 = lane & 15;

    const int pb = row0 + wave * 16 + l16;             // pair index within offset k
    const int pc = (pb < PPAIR) ? pb : (PPAIR - 1);
    const int g  = in_idx[kp + pc];

    const unsigned short* arow  = fb + (size_t)g * 96 + quad * 8;
    const unsigned short* bbase = wt + (size_t)k * 9216 + l16 * 96 + quad * 8;

    f32x4 acc[6];
#pragma unroll
    for (int n = 0; n < 6; n++) acc[n] = (f32x4){0.f, 0.f, 0.f, 0.f};

#pragma unroll
    for (int kk = 0; kk < 3; kk++) {
        bf16x8 a = *(const bf16x8*)(arow + kk * 32);
#pragma unroll
        for (int n = 0; n < 6; n++) {
            bf16x8 b = *(const bf16x8*)(bbase + n * 16 * 96 + kk * 32);
            // swapped operands: acc[n] = (W^T)(feats^T) block -> D^T
            acc[n] = __builtin_amdgcn_mfma_f32_16x16x32_bf16(b, a, acc[n], 0, 0, 0);
        }
    }

    if (pb < PPAIR) {
        unsigned short* crow = contrib + (size_t)(kp + pb) * 96 + quad * 4;
#pragma unroll
        for (int n = 0; n < 6; n++) {
            u32x2 v;
            v.x = (unsigned)f2b(acc[n][0]) | ((unsigned)f2b(acc[n][1]) << 16);
            v.y = (unsigned)f2b(acc[n][2]) | ((unsigned)f2b(acc[n][3]) << 16);
            __builtin_nontemporal_store(v, (u32x2*)(crow + n * 16));
        }
    }
}

// ---- Phase B: slab GATHER reduction + fused BN stats ----------------------
// block 384: rl = t/24 in [0,16) rows in flight, c4 = t%24 -> 4 channels/lane.
// Entries of a slab are gathered via perm (random 192B rows, no RMW cost).
__global__ __launch_bounds__(384) void reduce_bn(
    const unsigned short* __restrict__ contrib,
    const int* __restrict__ csr,
    const int* __restrict__ perm,
    float* __restrict__ out,
    float* __restrict__ sums)
{
    __shared__ float lsum[96], lq[96];
    int t = threadIdx.x;
    int rl = t / 24, c4 = t - rl * 24;
    float ps0 = 0.f, ps1 = 0.f, ps2 = 0.f, ps3 = 0.f;
    float pq0 = 0.f, pq1 = 0.f, pq2 = 0.f, pq3 = 0.f;

    for (int rb = blockIdx.x * 16; rb < N_OUT; rb += gridDim.x * 16) {
        int r = rb + rl;                       // N_OUT % 16 == 0
        int s = csr[r], e = csr[r + 1];
        float a0 = 0.f, a1 = 0.f, a2 = 0.f, a3 = 0.f;
        int j = s;
        for (; j + 1 < e; j += 2) {
            int p0 = perm[j], p1 = perm[j + 1];
            unsigned long long u = __builtin_nontemporal_load(
                (const unsigned long long*)(contrib + (size_t)p0 * 96 + c4 * 4));
            unsigned long long v = __builtin_nontemporal_load(
                (const unsigned long long*)(contrib + (size_t)p1 * 96 + c4 * 4));
            unsigned ux = (unsigned)u, uy = (unsigned)(u >> 32);
            unsigned vx = (unsigned)v, vy = (unsigned)(v >> 32);
            a0 += b_lo(ux); a1 += b_hi(ux); a2 += b_lo(uy); a3 += b_hi(uy);
            a0 += b_lo(vx); a1 += b_hi(vx); a2 += b_lo(vy); a3 += b_hi(vy);
        }
        if (j < e) {
            int p0 = perm[j];
            unsigned long long u = __builtin_nontemporal_load(
                (const unsigned long long*)(contrib + (size_t)p0 * 96 + c4 * 4));
            unsigned ux = (unsigned)u, uy = (unsigned)(u >> 32);
            a0 += b_lo(ux); a1 += b_hi(ux); a2 += b_lo(uy); a3 += b_hi(uy);
        }
        *(float4*)(out + (size_t)r * 96 + c4 * 4) = make_float4(a0, a1, a2, a3);
        ps0 += a0; ps1 += a1; ps2 += a2; ps3 += a3;
        pq0 += a0 * a0; pq1 += a1 * a1; pq2 += a2 * a2; pq3 += a3 * a3;
    }

    if (t < 96) { lsum[t] = 0.f; lq[t] = 0.f; }
    __syncthreads();
    atomicAdd(&lsum[c4 * 4 + 0], ps0); atomicAdd(&lsum[c4 * 4 + 1], ps1);
    atomicAdd(&lsum[c4 * 4 + 2], ps2); atomicAdd(&lsum[c4 * 4 + 3], ps3);
    atomicAdd(&lq[c4 * 4 + 0], pq0);   atomicAdd(&lq[c4 * 4 + 1], pq1);
    atomicAdd(&lq[c4 * 4 + 2], pq2);   atomicAdd(&lq[c4 * 4 + 3], pq3);
    __syncthreads();
    if (t < 96) {
        atomicAdd(&sums[t], lsum[t]);
        atomicAdd(&sums[96 + t], lq[t]);
    }
}

__global__ void bn_final(float* __restrict__ sums, const float* __restrict__ gamma,
                         const float* __restrict__ beta) {
    int c = threadIdx.x;
    if (c < 96) {
        float mean = sums[c] * (1.0f / (float)N_OUT);
        float var  = sums[96 + c] * (1.0f / (float)N_OUT) - mean * mean;
        float inv  = rsqrtf(var + BN_EPS);
        float sc   = inv * gamma[c];
        sums[c]      = sc;
        sums[96 + c] = beta[c] - mean * sc;
    }
}

__global__ void bn_apply(float* __restrict__ out, const float* __restrict__ sums) {
    int t = blockIdx.x * 256 + threadIdx.x;
    int g = t % 24;
    float sc0 = sums[g * 4 + 0], sc1 = sums[g * 4 + 1];
    float sc2 = sums[g * 4 + 2], sc3 = sums[g * 4 + 3];
    float sh0 = sums[96 + g * 4 + 0], sh1 = sums[96 + g * 4 + 1];
    float sh2 = sums[96 + g * 4 + 2], sh3 = sums[96 + g * 4 + 3];
    f32x4* o4 = (f32x4*)out;
    for (long f = t; f < 14400000L; f += 258048) {
        f32x4 v = __builtin_nontemporal_load(o4 + f);
        v.x = fmaxf(v.x * sc0 + sh0, 0.f);
        v.y = fmaxf(v.y * sc1 + sh1, 0.f);
        v.z = fmaxf(v.z * sc2 + sh2, 0.f);
        v.w = fmaxf(v.w * sc3 + sh3, 0.f);
        __builtin_nontemporal_store(v, o4 + f);
    }
}

extern "C" void kernel_launch(void* const* d_in, const int* in_sizes, int n_in,
                              void* d_out, int out_size, void* d_ws, size_t ws_size,
                              hipStream_t stream) {
    const float* feats  = (const float*)d_in[0];
    const int* in_idx   = (const int*)d_in[1];
    const int* out_idx  = (const int*)d_in[2];
    const float* weight = (const float*)d_in[3];
    const float* gamma  = (const float*)d_in[4];
    const float* beta   = (const float*)d_in[5];
    float* out = (float*)d_out;

    char* ws = (char*)d_ws;
    size_t off = 0;
    unsigned short* fb      = (unsigned short*)(ws + off); off += 38400000;
    unsigned short* wt      = (unsigned short*)(ws + off); off += 497664;
    unsigned short* contrib = (unsigned short*)(ws + off); off += (size_t)NPAIR * 96 * 2;
    int* csr                = (int*)(ws + off); off += 2400016;   // doubles as counts (in-place scan)
    int* bsum               = (int*)(ws + off); off += 4096;
    int* bsum_ex            = (int*)(ws + off); off += 4096;
    unsigned char* lrank    = (unsigned char*)(ws + off); off += NPAIR;          // 4.05 MB
    int* perm               = (int*)(ws + off); off += (size_t)NPAIR * 4;        // 16.2 MB
    float* sums             = (float*)(ws + off); off += 768;

    hipMemsetAsync(csr, 0, (size_t)N_OUT * sizeof(int), stream);
    hipMemsetAsync(sums, 0, 192 * sizeof(float), stream);

    cvt_feats<<<9375, 256, 0, stream>>>(feats, fb);
    cvt_w<<<972, 256, 0, stream>>>(weight, wt);

    k_hist<<<(NPAIR + 255) / 256, 256, 0, stream>>>(out_idx, csr, lrank);
    k_bsum<<<586, 256, 0, stream>>>(csr, bsum);
    k_scan_bsum<<<1, 1024, 0, stream>>>(bsum, bsum_ex);
    k_scan_local<<<586, 256, 0, stream>>>(csr, bsum_ex);
    k_perm<<<(NPAIR + 255) / 256, 256, 0, stream>>>(out_idx, lrank, csr, perm);

    contrib_k<<<dim3(2344, KOFF), 256, 0, stream>>>(fb, wt, in_idx, contrib);

    reduce_bn<<<9375, 384, 0, stream>>>(contrib, csr, perm, out, sums);
    bn_final<<<1, 128, 0, stream>>>(sums, gamma, beta);
    bn_apply<<<1008, 256, 0, stream>>>(out, sums);
}

// Round 5
// 1458.057 us; speedup vs baseline: 1.0947x; 1.0947x over previous
//
#include <hip/hip_runtime.h>
#include <hip/hip_bf16.h>

#define N_IN   200000
#define N_OUT  600000
#define KOFF   27
#define PPAIR  150000
#define NPAIR  (KOFF * PPAIR)       // 4,050,000
#define C      96
#define BN_EPS 1e-5f

using bf16x8 = __attribute__((ext_vector_type(8))) __bf16;
using f32x4  = __attribute__((ext_vector_type(4))) float;
using u32x2  = __attribute__((ext_vector_type(2))) unsigned int;
using u32x4  = __attribute__((ext_vector_type(4))) unsigned int;

static __device__ __forceinline__ unsigned short f2b(float x) {
    __hip_bfloat16 h = __float2bfloat16(x);
    return *reinterpret_cast<unsigned short*>(&h);
}
static __device__ __forceinline__ float b_lo(unsigned int u) { return __uint_as_float(u << 16); }
static __device__ __forceinline__ float b_hi(unsigned int u) { return __uint_as_float(u & 0xffff0000u); }

// ---- feats fp32 -> bf16, 8 elems/thread. 19,200,000 = 9375*256*8 exactly.
__global__ void cvt_feats(const float* __restrict__ src, unsigned short* __restrict__ dst) {
    int t = blockIdx.x * 256 + threadIdx.x;
    const float4* s4 = (const float4*)src;
    float4 a = s4[2 * t], b = s4[2 * t + 1];
    union { unsigned short u[8]; uint4 v; } r;
    r.u[0] = f2b(a.x); r.u[1] = f2b(a.y); r.u[2] = f2b(a.z); r.u[3] = f2b(a.w);
    r.u[4] = f2b(b.x); r.u[5] = f2b(b.y); r.u[6] = f2b(b.z); r.u[7] = f2b(b.w);
    ((uint4*)dst)[t] = r.v;
}

// ---- weight [k][c_in][c_out] fp32 -> wt [k][c_out][c_in] bf16
__global__ void cvt_w(const float* __restrict__ w, unsigned short* __restrict__ wt) {
    int t = blockIdx.x * 256 + threadIdx.x;   // 972*256 = 248832 exactly
    int k = t / 9216;
    int rem = t - k * 9216;
    int o = rem / 96;
    int i = rem - o * 96;
    wt[t] = f2b(w[k * 9216 + i * 96 + o]);
}

// ---- counting sort metadata ----------------------------------------------
__global__ void k_hist(const int* __restrict__ out_idx, int* __restrict__ counts,
                       unsigned char* __restrict__ lrank) {
    int t = blockIdx.x * 256 + threadIdx.x;
    if (t < NPAIR) lrank[t] = (unsigned char)atomicAdd(&counts[out_idx[t]], 1);
}

__global__ void k_bsum(const int* __restrict__ counts, int* __restrict__ bsum) {
    __shared__ int ls[256];
    int b = blockIdx.x, t = threadIdx.x;
    int base = b * 1024 + t * 4;
    int s = 0;
#pragma unroll
    for (int j = 0; j < 4; j++) { int i = base + j; if (i < N_OUT) s += counts[i]; }
    ls[t] = s;
    __syncthreads();
    for (int off = 128; off > 0; off >>= 1) {
        if (t < off) ls[t] += ls[t + off];
        __syncthreads();
    }
    if (t == 0) bsum[b] = ls[0];
}

__global__ void k_scan_bsum(const int* __restrict__ bsum, int* __restrict__ bsum_ex) {
    __shared__ int sc[1024];
    int t = threadIdx.x;
    int v = (t < 586) ? bsum[t] : 0;
    sc[t] = v;
    __syncthreads();
    for (int off = 1; off < 1024; off <<= 1) {
        int add = (t >= off) ? sc[t - off] : 0;
        __syncthreads();
        sc[t] += add;
        __syncthreads();
    }
    bsum_ex[t] = sc[t] - v;   // exclusive
}

// IN-PLACE: csr aliases counts (reads happen before first barrier, writes after).
__global__ void k_scan_local(int* __restrict__ csr, const int* __restrict__ bsum_ex) {
    __shared__ int sc[256];
    int b = blockIdx.x, t = threadIdx.x;
    int base = b * 1024 + t * 4;
    int c[4];
    int s = 0;
#pragma unroll
    for (int j = 0; j < 4; j++) {
        int i = base + j;
        c[j] = (i < N_OUT) ? csr[i] : 0;
        s += c[j];
    }
    sc[t] = s;
    __syncthreads();
    for (int off = 1; off < 256; off <<= 1) {
        int add = (t >= off) ? sc[t - off] : 0;
        __syncthreads();
        sc[t] += add;
        __syncthreads();
    }
    int run = bsum_ex[b] + sc[t] - s;
#pragma unroll
    for (int j = 0; j < 4; j++) {
        int i = base + j;
        if (i < N_OUT) {
            csr[i] = run;
            run += c[j];
            if (i == N_OUT - 1) csr[N_OUT] = run;
        }
    }
}

// perm[sorted_pos] = pair index (deterministic: same order as previous rounds).
__global__ void k_perm(const int* __restrict__ out_idx, const unsigned char* __restrict__ lrank,
                       const int* __restrict__ csr, int* __restrict__ perm) {
    int t = blockIdx.x * 256 + threadIdx.x;
    if (t < NPAIR) perm[csr[out_idx[t]] + (int)lrank[t]] = t;
}

// ---- Phase A: gather -> transposed MFMA -> LDS tile -> lane-linear NT store
// contrib written in PAIR order. Each wave owns a 16-row x 192B = 3072B LDS
// tile; after MFMA it packs accumulators into the tile (row-major), then
// reads back LANE-LINEAR and NT-stores 3 x 1024B contiguous per wave: every
// store instruction covers 8 FULL 128B lines -> NT's no-allocate fetch
// without partial-granule write amplification.
__global__ __launch_bounds__(256, 8) void contrib_k(
    const unsigned short* __restrict__ fb,   // feats bf16 [N_IN][96]
    const unsigned short* __restrict__ wt,   // weight bf16 [27][96(out)][96(in)]
    const int* __restrict__ in_idx,
    unsigned short* __restrict__ contrib)    // [NPAIR][96] bf16, PAIR order
{
    __shared__ __align__(16) unsigned int lds[4][768];   // 4 waves x 3072B

    const int t    = threadIdx.x;
    const int k    = blockIdx.y;
    const int row0 = blockIdx.x * 64;
    const long kp  = (long)k * PPAIR;

    const int wave = t >> 6, lane = t & 63;
    const int quad = lane >> 4, l16 = lane & 15;

    const int pb = row0 + wave * 16 + l16;             // pair index within offset k
    const int pc = (pb < PPAIR) ? pb : (PPAIR - 1);
    const int g  = in_idx[kp + pc];

    const unsigned short* arow  = fb + (size_t)g * 96 + quad * 8;
    const unsigned short* bbase = wt + (size_t)k * 9216 + l16 * 96 + quad * 8;

    f32x4 acc[6];
#pragma unroll
    for (int n = 0; n < 6; n++) acc[n] = (f32x4){0.f, 0.f, 0.f, 0.f};

#pragma unroll
    for (int kk = 0; kk < 3; kk++) {
        bf16x8 a = *(const bf16x8*)(arow + kk * 32);
#pragma unroll
        for (int n = 0; n < 6; n++) {
            bf16x8 b = *(const bf16x8*)(bbase + n * 16 * 96 + kk * 32);
            // swapped operands: acc[n] = (W^T)(feats^T) block -> D^T
            acc[n] = __builtin_amdgcn_mfma_f32_16x16x32_bf16(b, a, acc[n], 0, 0, 0);
        }
    }

    // pack into per-wave LDS tile: row l16, bytes n*32 + quad*8
    // word index = l16*48 + n*8 + quad*2
#pragma unroll
    for (int n = 0; n < 6; n++) {
        u32x2 v;
        v.x = (unsigned)f2b(acc[n][0]) | ((unsigned)f2b(acc[n][1]) << 16);
        v.y = (unsigned)f2b(acc[n][2]) | ((unsigned)f2b(acc[n][3]) << 16);
        *(u32x2*)&lds[wave][l16 * 48 + n * 8 + quad * 2] = v;
    }
    __syncthreads();   // cross-lane LDS visibility (whole block, one barrier)

    // lane-linear readback + NT store: tile of 16 rows is 192*16 B = 12 u32x4/row
    const int tile_row0 = row0 + wave * 16;
    if (tile_row0 + 16 <= PPAIR) {     // exact: tail wave is wholly invalid
        u32x4* cbase = (u32x4*)contrib;
        const size_t tb = (size_t)(kp + tile_row0) * 12;
#pragma unroll
        for (int s = 0; s < 3; s++) {
            u32x4 v = *(u32x4*)&lds[wave][s * 256 + lane * 4];
            __builtin_nontemporal_store(v, cbase + tb + s * 64 + lane);
        }
    }
}

// ---- Phase B: slab GATHER reduction + fused BN stats ----------------------
// block 384: rl = t/24 in [0,16) rows in flight, c4 = t%24 -> 4 channels/lane.
// Cached (non-NT) loads: adjacent sorted rows share 128B lines (3 lines per
// 2 rows) -> L2 captures the sharing.
__global__ __launch_bounds__(384) void reduce_bn(
    const unsigned short* __restrict__ contrib,
    const int* __restrict__ csr,
    const int* __restrict__ perm,
    float* __restrict__ out,
    float* __restrict__ sums)
{
    __shared__ float lsum[96], lq[96];
    int t = threadIdx.x;
    int rl = t / 24, c4 = t - rl * 24;
    float ps0 = 0.f, ps1 = 0.f, ps2 = 0.f, ps3 = 0.f;
    float pq0 = 0.f, pq1 = 0.f, pq2 = 0.f, pq3 = 0.f;

    for (int rb = blockIdx.x * 16; rb < N_OUT; rb += gridDim.x * 16) {
        int r = rb + rl;                       // N_OUT % 16 == 0
        int s = csr[r], e = csr[r + 1];
        float a0 = 0.f, a1 = 0.f, a2 = 0.f, a3 = 0.f;
        int j = s;
        for (; j + 1 < e; j += 2) {
            int p0 = perm[j], p1 = perm[j + 1];
            uint2 u = *(const uint2*)(contrib + (size_t)p0 * 96 + c4 * 4);
            uint2 v = *(const uint2*)(contrib + (size_t)p1 * 96 + c4 * 4);
            a0 += b_lo(u.x); a1 += b_hi(u.x); a2 += b_lo(u.y); a3 += b_hi(u.y);
            a0 += b_lo(v.x); a1 += b_hi(v.x); a2 += b_lo(v.y); a3 += b_hi(v.y);
        }
        if (j < e) {
            int p0 = perm[j];
            uint2 u = *(const uint2*)(contrib + (size_t)p0 * 96 + c4 * 4);
            a0 += b_lo(u.x); a1 += b_hi(u.x); a2 += b_lo(u.y); a3 += b_hi(u.y);
        }
        *(float4*)(out + (size_t)r * 96 + c4 * 4) = make_float4(a0, a1, a2, a3);
        ps0 += a0; ps1 += a1; ps2 += a2; ps3 += a3;
        pq0 += a0 * a0; pq1 += a1 * a1; pq2 += a2 * a2; pq3 += a3 * a3;
    }

    if (t < 96) { lsum[t] = 0.f; lq[t] = 0.f; }
    __syncthreads();
    atomicAdd(&lsum[c4 * 4 + 0], ps0); atomicAdd(&lsum[c4 * 4 + 1], ps1);
    atomicAdd(&lsum[c4 * 4 + 2], ps2); atomicAdd(&lsum[c4 * 4 + 3], ps3);
    atomicAdd(&lq[c4 * 4 + 0], pq0);   atomicAdd(&lq[c4 * 4 + 1], pq1);
    atomicAdd(&lq[c4 * 4 + 2], pq2);   atomicAdd(&lq[c4 * 4 + 3], pq3);
    __syncthreads();
    if (t < 96) {
        atomicAdd(&sums[t], lsum[t]);
        atomicAdd(&sums[96 + t], lq[t]);
    }
}

__global__ void bn_final(float* __restrict__ sums, const float* __restrict__ gamma,
                         const float* __restrict__ beta) {
    int c = threadIdx.x;
    if (c < 96) {
        float mean = sums[c] * (1.0f / (float)N_OUT);
        float var  = sums[96 + c] * (1.0f / (float)N_OUT) - mean * mean;
        float inv  = rsqrtf(var + BN_EPS);
        float sc   = inv * gamma[c];
        sums[c]      = sc;
        sums[96 + c] = beta[c] - mean * sc;
    }
}

__global__ void bn_apply(float* __restrict__ out, const float* __restrict__ sums) {
    int t = blockIdx.x * 256 + threadIdx.x;
    int g = t % 24;
    float sc0 = sums[g * 4 + 0], sc1 = sums[g * 4 + 1];
    float sc2 = sums[g * 4 + 2], sc3 = sums[g * 4 + 3];
    float sh0 = sums[96 + g * 4 + 0], sh1 = sums[96 + g * 4 + 1];
    float sh2 = sums[96 + g * 4 + 2], sh3 = sums[96 + g * 4 + 3];
    f32x4* o4 = (f32x4*)out;
    for (long f = t; f < 14400000L; f += 258048) {
        f32x4 v = __builtin_nontemporal_load(o4 + f);
        v.x = fmaxf(v.x * sc0 + sh0, 0.f);
        v.y = fmaxf(v.y * sc1 + sh1, 0.f);
        v.z = fmaxf(v.z * sc2 + sh2, 0.f);
        v.w = fmaxf(v.w * sc3 + sh3, 0.f);
        __builtin_nontemporal_store(v, o4 + f);
    }
}

extern "C" void kernel_launch(void* const* d_in, const int* in_sizes, int n_in,
                              void* d_out, int out_size, void* d_ws, size_t ws_size,
                              hipStream_t stream) {
    const float* feats  = (const float*)d_in[0];
    const int* in_idx   = (const int*)d_in[1];
    const int* out_idx  = (const int*)d_in[2];
    const float* weight = (const float*)d_in[3];
    const float* gamma  = (const float*)d_in[4];
    const float* beta   = (const float*)d_in[5];
    float* out = (float*)d_out;

    char* ws = (char*)d_ws;
    size_t off = 0;
    unsigned short* fb      = (unsigned short*)(ws + off); off += 38400000;
    unsigned short* wt      = (unsigned short*)(ws + off); off += 497664;
    unsigned short* contrib = (unsigned short*)(ws + off); off += (size_t)NPAIR * 96 * 2;
    int* csr                = (int*)(ws + off); off += 2400016;   // doubles as counts (in-place scan)
    int* bsum               = (int*)(ws + off); off += 4096;
    int* bsum_ex            = (int*)(ws + off); off += 4096;
    unsigned char* lrank    = (unsigned char*)(ws + off); off += NPAIR;          // 4.05 MB
    int* perm               = (int*)(ws + off); off += (size_t)NPAIR * 4;        // 16.2 MB
    float* sums             = (float*)(ws + off); off += 768;

    hipMemsetAsync(csr, 0, (size_t)N_OUT * sizeof(int), stream);
    hipMemsetAsync(sums, 0, 192 * sizeof(float), stream);

    cvt_feats<<<9375, 256, 0, stream>>>(feats, fb);
    cvt_w<<<972, 256, 0, stream>>>(weight, wt);

    k_hist<<<(NPAIR + 255) / 256, 256, 0, stream>>>(out_idx, csr, lrank);
    k_bsum<<<586, 256, 0, stream>>>(csr, bsum);
    k_scan_bsum<<<1, 1024, 0, stream>>>(bsum, bsum_ex);
    k_scan_local<<<586, 256, 0, stream>>>(csr, bsum_ex);
    k_perm<<<(NPAIR + 255) / 256, 256, 0, stream>>>(out_idx, lrank, csr, perm);

    contrib_k<<<dim3(2344, KOFF), 256, 0, stream>>>(fb, wt, in_idx, contrib);

    reduce_bn<<<9375, 384, 0, stream>>>(contrib, csr, perm, out, sums);
    bn_final<<<1, 128, 0, stream>>>(sums, gamma, beta);
    bn_apply<<<1008, 256, 0, stream>>>(out, sums);
}

// Round 6
// 1307.701 us; speedup vs baseline: 1.2206x; 1.1150x over previous
//
#include <hip/hip_runtime.h>
#include <hip/hip_bf16.h>

#define N_IN   200000
#define N_OUT  600000
#define KOFF   27
#define PPAIR  150000
#define NPAIR  (KOFF * PPAIR)       // 4,050,000
#define C      96
#define BN_EPS 1e-5f

using bf16x8 = __attribute__((ext_vector_type(8))) __bf16;
using f32x4  = __attribute__((ext_vector_type(4))) float;
using u32x2  = __attribute__((ext_vector_type(2))) unsigned int;
using u32x4  = __attribute__((ext_vector_type(4))) unsigned int;

static __device__ __forceinline__ unsigned short f2b(float x) {
    __hip_bfloat16 h = __float2bfloat16(x);
    return *reinterpret_cast<unsigned short*>(&h);
}
static __device__ __forceinline__ float b_lo(unsigned int u) { return __uint_as_float(u << 16); }
static __device__ __forceinline__ float b_hi(unsigned int u) { return __uint_as_float(u & 0xffff0000u); }

// ---- feats fp32 -> bf16, 8 elems/thread. 19,200,000 = 9375*256*8 exactly.
__global__ void cvt_feats(const float* __restrict__ src, unsigned short* __restrict__ dst) {
    int t = blockIdx.x * 256 + threadIdx.x;
    const float4* s4 = (const float4*)src;
    float4 a = s4[2 * t], b = s4[2 * t + 1];
    union { unsigned short u[8]; uint4 v; } r;
    r.u[0] = f2b(a.x); r.u[1] = f2b(a.y); r.u[2] = f2b(a.z); r.u[3] = f2b(a.w);
    r.u[4] = f2b(b.x); r.u[5] = f2b(b.y); r.u[6] = f2b(b.z); r.u[7] = f2b(b.w);
    ((uint4*)dst)[t] = r.v;
}

// ---- weight [k][c_in][c_out] fp32 -> wt [k][c_out][c_in] bf16
__global__ void cvt_w(const float* __restrict__ w, unsigned short* __restrict__ wt) {
    int t = blockIdx.x * 256 + threadIdx.x;   // 972*256 = 248832 exactly
    int k = t / 9216;
    int rem = t - k * 9216;
    int o = rem / 96;
    int i = rem - o * 96;
    wt[t] = f2b(w[k * 9216 + i * 96 + o]);
}

// ---- counting sort metadata ----------------------------------------------
__global__ void k_hist(const int* __restrict__ out_idx, int* __restrict__ counts,
                       unsigned char* __restrict__ lrank) {
    int t = blockIdx.x * 256 + threadIdx.x;
    if (t < NPAIR) lrank[t] = (unsigned char)atomicAdd(&counts[out_idx[t]], 1);
}

__global__ void k_bsum(const int* __restrict__ counts, int* __restrict__ bsum) {
    __shared__ int ls[256];
    int b = blockIdx.x, t = threadIdx.x;
    int base = b * 1024 + t * 4;
    int s = 0;
#pragma unroll
    for (int j = 0; j < 4; j++) { int i = base + j; if (i < N_OUT) s += counts[i]; }
    ls[t] = s;
    __syncthreads();
    for (int off = 128; off > 0; off >>= 1) {
        if (t < off) ls[t] += ls[t + off];
        __syncthreads();
    }
    if (t == 0) bsum[b] = ls[0];
}

__global__ void k_scan_bsum(const int* __restrict__ bsum, int* __restrict__ bsum_ex) {
    __shared__ int sc[1024];
    int t = threadIdx.x;
    int v = (t < 586) ? bsum[t] : 0;
    sc[t] = v;
    __syncthreads();
    for (int off = 1; off < 1024; off <<= 1) {
        int add = (t >= off) ? sc[t - off] : 0;
        __syncthreads();
        sc[t] += add;
        __syncthreads();
    }
    bsum_ex[t] = sc[t] - v;   // exclusive
}

// IN-PLACE: csr aliases counts (reads happen before first barrier, writes after).
__global__ void k_scan_local(int* __restrict__ csr, const int* __restrict__ bsum_ex) {
    __shared__ int sc[256];
    int b = blockIdx.x, t = threadIdx.x;
    int base = b * 1024 + t * 4;
    int c[4];
    int s = 0;
#pragma unroll
    for (int j = 0; j < 4; j++) {
        int i = base + j;
        c[j] = (i < N_OUT) ? csr[i] : 0;
        s += c[j];
    }
    sc[t] = s;
    __syncthreads();
    for (int off = 1; off < 256; off <<= 1) {
        int add = (t >= off) ? sc[t - off] : 0;
        __syncthreads();
        sc[t] += add;
        __syncthreads();
    }
    int run = bsum_ex[b] + sc[t] - s;
#pragma unroll
    for (int j = 0; j < 4; j++) {
        int i = base + j;
        if (i < N_OUT) {
            csr[i] = run;
            run += c[j];
            if (i == N_OUT - 1) csr[N_OUT] = run;
        }
    }
}

// perm[sorted_pos] = pair index (deterministic: same order as previous rounds).
__global__ void k_perm(const int* __restrict__ out_idx, const unsigned char* __restrict__ lrank,
                       const int* __restrict__ csr, int* __restrict__ perm) {
    int t = blockIdx.x * 256 + threadIdx.x;
    if (t < NPAIR) perm[csr[out_idx[t]] + (int)lrank[t]] = t;
}

// ---- Phase A: gather -> transposed MFMA -> LDS tile -> lane-linear NT store
__global__ __launch_bounds__(256, 8) void contrib_k(
    const unsigned short* __restrict__ fb,   // feats bf16 [N_IN][96]
    const unsigned short* __restrict__ wt,   // weight bf16 [27][96(out)][96(in)]
    const int* __restrict__ in_idx,
    unsigned short* __restrict__ contrib)    // [NPAIR][96] bf16, PAIR order
{
    __shared__ __align__(16) unsigned int lds[4][768];   // 4 waves x 3072B

    const int t    = threadIdx.x;
    const int k    = blockIdx.y;
    const int row0 = blockIdx.x * 64;
    const long kp  = (long)k * PPAIR;

    const int wave = t >> 6, lane = t & 63;
    const int quad = lane >> 4, l16 = lane & 15;

    const int pb = row0 + wave * 16 + l16;             // pair index within offset k
    const int pc = (pb < PPAIR) ? pb : (PPAIR - 1);
    const int g  = in_idx[kp + pc];

    const unsigned short* arow  = fb + (size_t)g * 96 + quad * 8;
    const unsigned short* bbase = wt + (size_t)k * 9216 + l16 * 96 + quad * 8;

    f32x4 acc[6];
#pragma unroll
    for (int n = 0; n < 6; n++) acc[n] = (f32x4){0.f, 0.f, 0.f, 0.f};

#pragma unroll
    for (int kk = 0; kk < 3; kk++) {
        bf16x8 a = *(const bf16x8*)(arow + kk * 32);
#pragma unroll
        for (int n = 0; n < 6; n++) {
            bf16x8 b = *(const bf16x8*)(bbase + n * 16 * 96 + kk * 32);
            acc[n] = __builtin_amdgcn_mfma_f32_16x16x32_bf16(b, a, acc[n], 0, 0, 0);
        }
    }

    // pack into per-wave LDS tile: row l16, word index = l16*48 + n*8 + quad*2
#pragma unroll
    for (int n = 0; n < 6; n++) {
        u32x2 v;
        v.x = (unsigned)f2b(acc[n][0]) | ((unsigned)f2b(acc[n][1]) << 16);
        v.y = (unsigned)f2b(acc[n][2]) | ((unsigned)f2b(acc[n][3]) << 16);
        *(u32x2*)&lds[wave][l16 * 48 + n * 8 + quad * 2] = v;
    }
    __syncthreads();

    // lane-linear readback + NT store: 3 x 1024B contiguous per wave
    const int tile_row0 = row0 + wave * 16;
    if (tile_row0 + 16 <= PPAIR) {
        u32x4* cbase = (u32x4*)contrib;
        const size_t tb = (size_t)(kp + tile_row0) * 12;
#pragma unroll
        for (int s = 0; s < 3; s++) {
            u32x4 v = *(u32x4*)&lds[wave][s * 256 + lane * 4];
            __builtin_nontemporal_store(v, cbase + tb + s * 64 + lane);
        }
    }
}

// ---- Phase B: max-MLP staged gather reduction + fused BN stats ------------
// Per 16-row group, sorted entries [csr[rb], csr[rb+16)) are CONTIGUOUS.
// Chunk of up to 128 entries: (1) stage perm values, (2) ALL 384 threads
// flat-gather the rows as independent u32x4 loads (4/thread, 1536 in flight
// per block) into LDS, (3) barrier, (4) per-(row,c4) threads reduce from LDS
// in ascending-j order (bit-identical summation order to the serial version).
#define RB_CHUNK 128
__global__ __launch_bounds__(384) void reduce_bn(
    const unsigned short* __restrict__ contrib,
    const int* __restrict__ csr,
    const int* __restrict__ perm,
    float* __restrict__ out,
    float* __restrict__ sums)
{
    __shared__ __align__(16) unsigned short stage[RB_CHUNK * 96];  // 24576 B
    __shared__ int   lperm[RB_CHUNK];
    __shared__ int   lcsr[17];
    __shared__ float lsum[96], lq[96];

    const int t  = threadIdx.x;
    const int rl = t / 24, c4 = t - rl * 24;   // 16 rows x 24 channel-quads

    float ps0 = 0.f, ps1 = 0.f, ps2 = 0.f, ps3 = 0.f;
    float pq0 = 0.f, pq1 = 0.f, pq2 = 0.f, pq3 = 0.f;

    for (int grp = blockIdx.x; grp < N_OUT / 16; grp += gridDim.x) {
        const int rb = grp * 16;
        if (t < 17) lcsr[t] = csr[rb + t];
        __syncthreads();
        const int s0 = lcsr[0], s1 = lcsr[16];
        const int rs = lcsr[rl], re = lcsr[rl + 1];

        float a0 = 0.f, a1 = 0.f, a2 = 0.f, a3 = 0.f;

        for (int cs = s0; cs < s1; cs += RB_CHUNK) {
            const int ce  = (cs + RB_CHUNK < s1) ? cs + RB_CHUNK : s1;
            const int n12 = (ce - cs) * 12;

            if (t < RB_CHUNK) lperm[t] = (cs + t < s1) ? perm[cs + t] : 0;
            __syncthreads();   // lperm ready; prev chunk fully consumed

            // flat gather: 4 independent 16B loads per thread
            const int i0 = t, i1 = t + 384, i2 = t + 768, i3 = t + 1152;
            const bool g0 = i0 < n12, g1 = i1 < n12, g2 = i2 < n12, g3 = i3 < n12;
            u32x4 v0, v1, v2, v3;
            if (g0) { int e = i0 / 12, s = i0 - (i0 / 12) * 12;
                      v0 = *(const u32x4*)(contrib + (size_t)lperm[e] * 96 + s * 8); }
            if (g1) { int e = i1 / 12, s = i1 - (i1 / 12) * 12;
                      v1 = *(const u32x4*)(contrib + (size_t)lperm[e] * 96 + s * 8); }
            if (g2) { int e = i2 / 12, s = i2 - (i2 / 12) * 12;
                      v2 = *(const u32x4*)(contrib + (size_t)lperm[e] * 96 + s * 8); }
            if (g3) { int e = i3 / 12, s = i3 - (i3 / 12) * 12;
                      v3 = *(const u32x4*)(contrib + (size_t)lperm[e] * 96 + s * 8); }
            if (g0) *(u32x4*)&stage[i0 * 8] = v0;
            if (g1) *(u32x4*)&stage[i1 * 8] = v1;
            if (g2) *(u32x4*)&stage[i2 * 8] = v2;
            if (g3) *(u32x4*)&stage[i3 * 8] = v3;
            __syncthreads();   // stage ready

            // consume: ascending-j order (deterministic)
            const int jb = (rs > cs) ? rs : cs;
            const int je = (re < ce) ? re : ce;
            for (int j = jb; j < je; j++) {
                const unsigned short* sp = stage + (size_t)(j - cs) * 96 + c4 * 4;
                uint2 u = *(const uint2*)sp;
                a0 += b_lo(u.x); a1 += b_hi(u.x); a2 += b_lo(u.y); a3 += b_hi(u.y);
            }
        }

        *(float4*)(out + (size_t)(rb + rl) * 96 + c4 * 4) = make_float4(a0, a1, a2, a3);
        ps0 += a0; ps1 += a1; ps2 += a2; ps3 += a3;
        pq0 += a0 * a0; pq1 += a1 * a1; pq2 += a2 * a2; pq3 += a3 * a3;
        __syncthreads();   // protect lcsr/stage before next group
    }

    if (t < 96) { lsum[t] = 0.f; lq[t] = 0.f; }
    __syncthreads();
    atomicAdd(&lsum[c4 * 4 + 0], ps0); atomicAdd(&lsum[c4 * 4 + 1], ps1);
    atomicAdd(&lsum[c4 * 4 + 2], ps2); atomicAdd(&lsum[c4 * 4 + 3], ps3);
    atomicAdd(&lq[c4 * 4 + 0], pq0);   atomicAdd(&lq[c4 * 4 + 1], pq1);
    atomicAdd(&lq[c4 * 4 + 2], pq2);   atomicAdd(&lq[c4 * 4 + 3], pq3);
    __syncthreads();
    if (t < 96) {
        atomicAdd(&sums[t], lsum[t]);
        atomicAdd(&sums[96 + t], lq[t]);
    }
}

__global__ void bn_final(float* __restrict__ sums, const float* __restrict__ gamma,
                         const float* __restrict__ beta) {
    int c = threadIdx.x;
    if (c < 96) {
        float mean = sums[c] * (1.0f / (float)N_OUT);
        float var  = sums[96 + c] * (1.0f / (float)N_OUT) - mean * mean;
        float inv  = rsqrtf(var + BN_EPS);
        float sc   = inv * gamma[c];
        sums[c]      = sc;
        sums[96 + c] = beta[c] - mean * sc;
    }
}

__global__ void bn_apply(float* __restrict__ out, const float* __restrict__ sums) {
    int t = blockIdx.x * 256 + threadIdx.x;
    int g = t % 24;
    float sc0 = sums[g * 4 + 0], sc1 = sums[g * 4 + 1];
    float sc2 = sums[g * 4 + 2], sc3 = sums[g * 4 + 3];
    float sh0 = sums[96 + g * 4 + 0], sh1 = sums[96 + g * 4 + 1];
    float sh2 = sums[96 + g * 4 + 2], sh3 = sums[96 + g * 4 + 3];
    f32x4* o4 = (f32x4*)out;
    for (long f = t; f < 14400000L; f += 258048) {
        f32x4 v = __builtin_nontemporal_load(o4 + f);
        v.x = fmaxf(v.x * sc0 + sh0, 0.f);
        v.y = fmaxf(v.y * sc1 + sh1, 0.f);
        v.z = fmaxf(v.z * sc2 + sh2, 0.f);
        v.w = fmaxf(v.w * sc3 + sh3, 0.f);
        __builtin_nontemporal_store(v, o4 + f);
    }
}

extern "C" void kernel_launch(void* const* d_in, const int* in_sizes, int n_in,
                              void* d_out, int out_size, void* d_ws, size_t ws_size,
                              hipStream_t stream) {
    const float* feats  = (const float*)d_in[0];
    const int* in_idx   = (const int*)d_in[1];
    const int* out_idx  = (const int*)d_in[2];
    const float* weight = (const float*)d_in[3];
    const float* gamma  = (const float*)d_in[4];
    const float* beta   = (const float*)d_in[5];
    float* out = (float*)d_out;

    char* ws = (char*)d_ws;
    size_t off = 0;
    unsigned short* fb      = (unsigned short*)(ws + off); off += 38400000;
    unsigned short* wt      = (unsigned short*)(ws + off); off += 497664;
    unsigned short* contrib = (unsigned short*)(ws + off); off += (size_t)NPAIR * 96 * 2;
    int* csr                = (int*)(ws + off); off += 2400016;   // doubles as counts (in-place scan)
    int* bsum               = (int*)(ws + off); off += 4096;
    int* bsum_ex            = (int*)(ws + off); off += 4096;
    unsigned char* lrank    = (unsigned char*)(ws + off); off += NPAIR;          // 4.05 MB
    int* perm               = (int*)(ws + off); off += (size_t)NPAIR * 4;        // 16.2 MB
    float* sums             = (float*)(ws + off); off += 768;

    hipMemsetAsync(csr, 0, (size_t)N_OUT * sizeof(int), stream);
    hipMemsetAsync(sums, 0, 192 * sizeof(float), stream);

    cvt_feats<<<9375, 256, 0, stream>>>(feats, fb);
    cvt_w<<<972, 256, 0, stream>>>(weight, wt);

    k_hist<<<(NPAIR + 255) / 256, 256, 0, stream>>>(out_idx, csr, lrank);
    k_bsum<<<586, 256, 0, stream>>>(csr, bsum);
    k_scan_bsum<<<1, 1024, 0, stream>>>(bsum, bsum_ex);
    k_scan_local<<<586, 256, 0, stream>>>(csr, bsum_ex);
    k_perm<<<(NPAIR + 255) / 256, 256, 0, stream>>>(out_idx, lrank, csr, perm);

    contrib_k<<<dim3(2344, KOFF), 256, 0, stream>>>(fb, wt, in_idx, contrib);

    reduce_bn<<<2500, 384, 0, stream>>>(contrib, csr, perm, out, sums);
    bn_final<<<1, 128, 0, stream>>>(sums, gamma, beta);
    bn_apply<<<1008, 256, 0, stream>>>(out, sums);
}